// Round 13
// baseline (1520.238 us; speedup 1.0000x reference)
//
#include <hip/hip_runtime.h>
#include <hip/hip_bf16.h>

#define NB   131072
#define TPB  1024
#define SPB  256

typedef __attribute__((ext_vector_type(8))) short short8;
typedef __attribute__((ext_vector_type(4))) float f32x4;
typedef __attribute__((ext_vector_type(4))) unsigned short ushort4v;

__device__ __forceinline__ unsigned short f2bf(float f) {
    union { float f; unsigned int u; } v; v.f = f;
    unsigned int r = v.u + 0x7fff + ((v.u >> 16) & 1);   // RNE
    return (unsigned short)(r >> 16);
}

__device__ __forceinline__ unsigned int cvt_pk_bf16(float lo, float hi) {
    unsigned int r;
    asm("v_cvt_pk_bf16_f32 %0, %1, %2" : "=v"(r) : "v"(lo), "v"(hi));
    return r;
}
// native 2^x / log2(x) (v_exp_f32 / v_log_f32 are base-2)
__device__ __forceinline__ float fexp2(float x) {
    float r; asm("v_exp_f32 %0, %1" : "=v"(r) : "v"(x)); return r;
}
__device__ __forceinline__ float flog2(float x) {
    float r; asm("v_log_f32 %0, %1" : "=v"(r) : "v"(x)); return r;
}

// ws layout (ushort elems): [0) Wk2 bf16 row-major [n][k]; [65536) Wk2^T [k][n];
// [131072) Wp2; [196608) Wp2^T.  512 KB, L2-resident.
__global__ void prep_weights(const float* __restrict__ Wk2, const float* __restrict__ Wp2,
                             unsigned short* __restrict__ out) {
    int idx = blockIdx.x * blockDim.x + threadIdx.x;   // 0..65535
    int n = idx >> 8, k = idx & 255;
    unsigned short a = f2bf(Wk2[idx]);
    out[idx] = a;
    out[65536 + k * 256 + n] = a;
    unsigned short b = f2bf(Wp2[idx]);
    out[131072 + idx] = b;
    out[196608 + k * 256 + n] = b;
}

// 2 blocks/CU for cross-block barrier overlap: SPB=256, grid=512, LDS 76 KB,
// __launch_bounds__(1024, 8) -> 32 waves/CU.  Pipeline machinery = R11 verbatim,
// 8 pairs of 16-row subtiles per path-loop.
// Subtile packed frag-order (16 rows x 256 cols = 4096 ushorts):
//   elem (m,k) at u*4096 + (k>>5)*512 + ((k>>3)&3)*128 + m*8 + (k&7)
// exp2-domain: HB stores h2 = log2(1+e^a); fwd MFMA output IS the layer-2 exp2
// argument (b2 pre-scaled); sigma(a1) recovered in phE as 1 - 2^(-h2).
__launch_bounds__(TPB, 8)
__global__ void phgn_main(const float* __restrict__ q_in, const float* __restrict__ p_in,
                          const float* __restrict__ u_in,
                          const float* __restrict__ Wk1, const float* __restrict__ bk1,
                          const float* __restrict__ bk2, const float* __restrict__ wk3,
                          const float* __restrict__ wp1, const float* __restrict__ bp1,
                          const float* __restrict__ bp2, const float* __restrict__ wp3,
                          const float* __restrict__ bctrl,
                          const unsigned short* __restrict__ Wmats,
                          float* __restrict__ out_q, float* __restrict__ out_p) {
    __shared__ unsigned short bufH0[8192], bufH1[8192];    // h2 tile-pairs, 16 KB each
    __shared__ unsigned short bufG0[8192], bufG1[8192];    // g2 tile-pairs
    __shared__ float2 qps[SPB];                            // RK stage state (q,p)
    __shared__ float  slot0[1024], slot1[1024];            // per-wave grad partials
    __shared__ float  dHacc[SPB * 2];                      // folded (dH/dq, dH/dp)

    const int tid  = threadIdx.x;
    const int lane = tid & 63;
    const int wave = tid >> 6;      // 0..15
    const int g    = lane >> 4;     // 0..3
    const int l15  = lane & 15;
    const int col  = wave * 16 + l15;   // 0..255
    // frag-order write base for this thread's column (R9/R11-proven)
    const int wbase = ((col >> 5) << 9) + (((col >> 3) & 3) << 7) + (col & 7);
    // phE read base: h2[kk = wave*16 + g*4 + r][m = l15], r=0..3 contiguous
    const int hbE = (wave >> 1) * 512 + ((wave & 1) * 2 + (g >> 1)) * 128
                  + l15 * 8 + 4 * (g & 1);
    // bpermute byte-indices for the A-frag gather
    const int idxLo = ((g << 5) | l15) << 2;
    const int idxHi = idxLo + 64;

    float q0 = 0.f, p0 = 0.f, uc = 0.f, accq = 0.f, accp = 0.f;
    if (tid < SPB) {
        const int sg = blockIdx.x * SPB + tid;
        q0 = q_in[sg]; p0 = p_in[sg];
        uc = u_in[sg] * bctrl[0];
        qps[tid] = make_float2(q0, p0);
    }
    __syncthreads();

    const float dt = 0.05f;
    const float LOG2E = 1.44269504f;

    #pragma unroll 1
    for (int st = 0; st < 4; ++st) {
        #pragma unroll 1
        for (int path = 0; path < 2; ++path) {
            const unsigned short* Wf = Wmats + path * 131072;  // row-major W2 [n][k]
            const unsigned short* Wb = Wf + 65536;             // row-major W2^T [k][n]
            // layer-1 params pre-scaled into exp2 domain (phase A only)
            const float wq  = (path ? wp1[col] : Wk1[2*col])   * LOG2E;
            const float wp  = (path ? 0.f      : Wk1[2*col+1]) * LOG2E;
            const float b1p = (path ? bp1[col] : bk1[col])     * LOG2E;
            const float w3  =  path ? wp3[col] : wk3[col];
            const float b2p = (path ? bp2[col] : bk2[col])     * LOG2E;

            // Weight fragments (R8-proven orientation)
            short8 wfr[8], wbr[8];
            #pragma unroll
            for (int ks = 0; ks < 8; ++ks) {
                wfr[ks] = *(const short8*)(Wf + col * 256 + ks * 32 + g * 8);
                wbr[ks] = *(const short8*)(Wb + col * 256 + ks * 32 + g * 8);
            }

            // w1 B-frag for the phE MFMA: B[k][c] = w1[wave*16+k][c], k<16, c<2 (else 0).
            short8 w1f;
            {
                union { int iv[4]; short8 sv; } uu;
                #pragma unroll
                for (int d = 0; d < 4; ++d) {
                    float lo = 0.f, hi = 0.f;
                    if (g < 2 && l15 < 2) {
                        const int k0 = wave * 16 + g * 8 + 2 * d;
                        if (path == 0) {
                            lo = Wk1[2*k0 + l15];
                            hi = Wk1[2*k0 + 2 + l15];
                        } else if (l15 == 0) {
                            lo = wp1[k0]; hi = wp1[k0 + 1];
                        }
                    }
                    uu.iv[d] = cvt_pk_bf16(lo, hi);
                }
                w1f = uu.sv;
            }

            f32x4 ac, bc;

            // phase A: h2 = log2(1+2^a) for pair -> HB
            auto phA = [&](int pair, unsigned short* HB) {
                const int mb = pair * 32;
                #pragma unroll
                for (int u = 0; u < 2; ++u) {
                    #pragma unroll
                    for (int r = 0; r < 4; r += 2) {
                        const float4 qq = *(const float4*)&qps[mb + u*16 + g*4 + r];
                        const float a0 = fmaf(wq, qq.x, fmaf(wp, qq.y, b1p));
                        const float a1 = fmaf(wq, qq.z, fmaf(wp, qq.w, b1p));
                        const float h0 = flog2(1.0f + fexp2(a0));
                        const float h1 = flog2(1.0f + fexp2(a1));
                        const unsigned int pk = cvt_pk_bf16(h0, h1);
                        HB[u*4096 + wbase + (g*4 + r    ) * 8] = (unsigned short)(pk & 0xffffu);
                        HB[u*4096 + wbase + (g*4 + r + 1) * 8] = (unsigned short)(pk >> 16);
                    }
                }
            };
            // phase B: fwd GEMM on subtile u
            auto phB = [&](const unsigned short* HB, int u) {
                ac = (f32x4){0.f, 0.f, 0.f, 0.f};
                #pragma unroll
                for (int ks = 0; ks < 8; ++ks) {
                    const short8 af = *(const short8*)(HB + u*4096 + ks*512 + lane*8);
                    ac = __builtin_amdgcn_mfma_f32_16x16x32_bf16(af, wfr[ks], ac, 0,0,0);
                }
            };
            // phase C: g2 = w3 * sigmoid -> GB
            auto phC = [&](unsigned short* GB, int u) {
                #pragma unroll
                for (int r = 0; r < 4; r += 2) {
                    float gg[2];
                    #pragma unroll
                    for (int v = 0; v < 2; ++v) {
                        const float e = fexp2(ac[r+v] + b2p);
                        gg[v] = w3 * (e * __builtin_amdgcn_rcpf(1.0f + e));
                    }
                    const unsigned int pk = cvt_pk_bf16(gg[0], gg[1]);
                    GB[u*4096 + wbase + (g*4 + r    ) * 8] = (unsigned short)(pk & 0xffffu);
                    GB[u*4096 + wbase + (g*4 + r + 1) * 8] = (unsigned short)(pk >> 16);
                }
            };
            // phase D: bwd GEMM, transposed output via operand swap
            auto phD = [&](const unsigned short* GB, int u) {
                bc = (f32x4){0.f, 0.f, 0.f, 0.f};
                #pragma unroll
                for (int ns = 0; ns < 8; ++ns) {
                    const short8 ag = *(const short8*)(GB + u*4096 + ns*512 + lane*8);
                    bc = __builtin_amdgcn_mfma_f32_16x16x32_bf16(wbr[ns], ag, bc, 0,0,0);
                }
            };
            // phase E: s1 = 1 - 2^(-h2); gather g1 to A-frag; MFMA vs w1f -> slot
            auto phE = [&](const unsigned short* HB, int u, float* slot) {
                const ushort4v hv = *(const ushort4v*)(HB + u*4096 + hbE);
                float v0, v1, v2, v3;
                {
                    const float h0 = __uint_as_float((unsigned)hv[0] << 16);
                    const float h1 = __uint_as_float((unsigned)hv[1] << 16);
                    const float h2 = __uint_as_float((unsigned)hv[2] << 16);
                    const float h3 = __uint_as_float((unsigned)hv[3] << 16);
                    v0 = bc[0] * (1.0f - fexp2(-h0));
                    v1 = bc[1] * (1.0f - fexp2(-h1));
                    v2 = bc[2] * (1.0f - fexp2(-h2));
                    v3 = bc[3] * (1.0f - fexp2(-h3));
                }
                const int pk01 = (int)cvt_pk_bf16(v0, v1);
                const int pk23 = (int)cvt_pk_bf16(v2, v3);
                union { int iv[4]; short8 sv; } af;
                af.iv[0] = __builtin_amdgcn_ds_bpermute(idxLo, pk01);
                af.iv[1] = __builtin_amdgcn_ds_bpermute(idxLo, pk23);
                af.iv[2] = __builtin_amdgcn_ds_bpermute(idxHi, pk01);
                af.iv[3] = __builtin_amdgcn_ds_bpermute(idxHi, pk23);
                f32x4 dd = (f32x4){0.f, 0.f, 0.f, 0.f};
                dd = __builtin_amdgcn_mfma_f32_16x16x32_bf16(af.sv, w1f, dd, 0,0,0);
                if (l15 < 2) {
                    #pragma unroll
                    for (int r = 0; r < 4; ++r)
                        slot[wave*64 + (u*16 + g*4 + r)*2 + l15] = dd[r];
                }
            };
            // phase F: fold 16 wave-partials of a PAIR into dHacc
            auto phF = [&](int pair, const float* slot) {
                if (tid < 64) {
                    const int m2 = tid >> 1, c = tid & 1;
                    if (path == 0 || c == 0) {
                        float s = 0.f;
                        #pragma unroll
                        for (int w = 0; w < 16; ++w) s += slot[w * 64 + tid];
                        const int di = (pair * 32 + m2) * 2 + c;
                        if (path == 0) dHacc[di] = s;
                        else           dHacc[di] += s;
                    }
                }
            };

            // ---- software pipeline over 8 pairs (R11 schedule, halved) ----
            phA(0, bufH0);
            __syncthreads();
            phB(bufH0,0); phC(bufG0,0); phB(bufH0,1); phC(bufG0,1);
            phA(1, bufH1);
            __syncthreads();

            #pragma unroll 1
            for (int k2 = 0; k2 < 3; ++k2) {
                const int j = 1 + 2*k2;   // odd region: pairs j / j-1 / j+1
                phB(bufH1,0); phD(bufG0,0); phC(bufG1,0); phE(bufH0, 0, slot0);
                phB(bufH1,1); phD(bufG0,1); phC(bufG1,1); phE(bufH0, 1, slot0);
                if (k2) phF(j - 2, slot1);
                phA(j + 1, bufH0);       // overwrite AFTER phE read (same-wave order)
                __syncthreads();
                // even region j+1
                phB(bufH0,0); phD(bufG1,0); phC(bufG0,0); phE(bufH1, 0, slot1);
                phB(bufH0,1); phD(bufG1,1); phC(bufG0,1); phE(bufH1, 1, slot1);
                phF(j - 1, slot0);
                phA(j + 2, bufH1);
                __syncthreads();
            }

            // pair 7 (odd): B/C(7), D/E(6), F(5)
            phB(bufH1,0); phD(bufG0,0); phC(bufG1,0); phE(bufH0, 0, slot0);
            phB(bufH1,1); phD(bufG0,1); phC(bufG1,1); phE(bufH0, 1, slot0);
            phF(5, slot1);
            __syncthreads();
            // drain: D/E(7), F(6)
            phD(bufG1,0); phE(bufH1, 0, slot1);
            phD(bufG1,1); phE(bufH1, 1, slot1);
            phF(6, slot0);
            __syncthreads();
            phF(7, slot1);
            __syncthreads();
        } // path

        // ---- stage combine: dq = dH/dp, dp = -dH/dq + u*bc; RK4 update
        if (tid < SPB) {
            const float dq = dHacc[tid * 2 + 1];
            const float dp = -dHacc[tid * 2 + 0] + uc;
            const float c = (st == 1 || st == 2) ? 2.f : 1.f;
            accq += c * dq; accp += c * dp;
            if (st < 3) {
                const float hh = (st == 2) ? dt : 0.5f * dt;
                qps[tid] = make_float2(q0 + hh * dq, p0 + hh * dp);
            }
        }
        __syncthreads();
    }

    if (tid < SPB) {
        const int sg = blockIdx.x * SPB + tid;
        out_q[sg] = q0 + (dt / 6.f) * accq;
        out_p[sg] = p0 + (dt / 6.f) * accp;
    }
}

extern "C" void kernel_launch(void* const* d_in, const int* in_sizes, int n_in,
                              void* d_out, int out_size, void* d_ws, size_t ws_size,
                              hipStream_t stream) {
    const float* q   = (const float*)d_in[0];
    const float* p   = (const float*)d_in[1];
    const float* u   = (const float*)d_in[2];
    const float* Wk1 = (const float*)d_in[3];
    const float* bk1 = (const float*)d_in[4];
    const float* Wk2 = (const float*)d_in[5];
    const float* bk2 = (const float*)d_in[6];
    const float* Wk3 = (const float*)d_in[7];
    const float* Wp1 = (const float*)d_in[9];
    const float* bp1 = (const float*)d_in[10];
    const float* Wp2 = (const float*)d_in[11];
    const float* bp2 = (const float*)d_in[12];
    const float* Wp3 = (const float*)d_in[13];
    const float* bc  = (const float*)d_in[15];

    unsigned short* wbf = (unsigned short*)d_ws;   // 512 KB used
    prep_weights<<<256, 256, 0, stream>>>(Wk2, Wp2, wbf);

    float* oq = (float*)d_out;
    phgn_main<<<NB / SPB, TPB, 0, stream>>>(q, p, u, Wk1, bk1, bk2, Wk3, Wp1, bp1, bp2, Wp3,
                                            bc, wbf, oq, oq + NB);
}

// Round 14
// 414.389 us; speedup vs baseline: 3.6686x; 3.6686x over previous
//
#include <hip/hip_runtime.h>
#include <hip/hip_bf16.h>

#define NB   131072
#define TPB  1024
#define SPB  512

typedef __attribute__((ext_vector_type(8))) short short8;
typedef __attribute__((ext_vector_type(4))) float f32x4;
typedef __attribute__((ext_vector_type(4))) unsigned short ushort4v;

__device__ __forceinline__ unsigned short f2bf(float f) {
    union { float f; unsigned int u; } v; v.f = f;
    unsigned int r = v.u + 0x7fff + ((v.u >> 16) & 1);   // RNE
    return (unsigned short)(r >> 16);
}

__device__ __forceinline__ unsigned int cvt_pk_bf16(float lo, float hi) {
    unsigned int r;
    asm("v_cvt_pk_bf16_f32 %0, %1, %2" : "=v"(r) : "v"(lo), "v"(hi));
    return r;
}
// native 2^x / log2(x) (v_exp_f32 / v_log_f32 are base-2)
__device__ __forceinline__ float fexp2(float x) {
    float r; asm("v_exp_f32 %0, %1" : "=v"(r) : "v"(x)); return r;
}
__device__ __forceinline__ float flog2(float x) {
    float r; asm("v_log_f32 %0, %1" : "=v"(r) : "v"(x)); return r;
}

// ws layout (ushort elems): [0) Wk2 bf16 row-major [n][k] (fwd, unscaled);
// [65536) Wk2^T·w3 [k][n] (bwd, w3-folded); [131072) Wp2; [196608) Wp2^T·wp3.
// 512 KB, L2-resident.
__global__ void prep_weights(const float* __restrict__ Wk2, const float* __restrict__ Wp2,
                             const float* __restrict__ wk3, const float* __restrict__ wp3,
                             unsigned short* __restrict__ out) {
    int idx = blockIdx.x * blockDim.x + threadIdx.x;   // 0..65535
    int n = idx >> 8, k = idx & 255;
    out[idx]                  = f2bf(Wk2[idx]);
    out[65536 + k * 256 + n]  = f2bf(Wk2[idx] * wk3[n]);
    out[131072 + idx]         = f2bf(Wp2[idx]);
    out[196608 + k * 256 + n] = f2bf(Wp2[idx] * wp3[n]);
}

// Wave w owns col-strip [16w,16w+16); col = 16w + l15 for MFMA-coupled phases
// (C, E).  Pair of 16-row subtiles (32 samples) per barrier region (R11 sched).
// Subtile packed frag-order (16 rows x 256 cols = 4096 ushorts):
//   elem (m,k) at u*4096 + (k>>5)*512 + ((k>>3)&3)*128 + m*8 + (k&7)
// exp2-domain: HB stores h2 = log2(1+e^a); fwd MFMA output IS the layer-2 exp2
// argument (b2 pre-scaled); sigma(a1) recovered in phE as 1 - 2^(-h2).
// Phase A uses a DECOUPLED col-pair map (2 cols x 4 rows per thread) so each
// packed bf16 pair is one ds_write_b32 (same dword).
__launch_bounds__(TPB, 4)
__global__ void phgn_main(const float* __restrict__ q_in, const float* __restrict__ p_in,
                          const float* __restrict__ u_in,
                          const float* __restrict__ Wk1, const float* __restrict__ bk1,
                          const float* __restrict__ bk2, const float* __restrict__ wk3,
                          const float* __restrict__ wp1, const float* __restrict__ bp1,
                          const float* __restrict__ bp2, const float* __restrict__ wp3,
                          const float* __restrict__ bctrl,
                          const unsigned short* __restrict__ Wmats,
                          float* __restrict__ out_q, float* __restrict__ out_p) {
    __shared__ unsigned short bufH0[8192], bufH1[8192];    // h2 tile-pairs, 16 KB each
    __shared__ unsigned short bufG0[8192], bufG1[8192];    // g2 tile-pairs
    __shared__ float2 qps[SPB];                            // RK stage state (q,p)
    __shared__ float2 q0p0[SPB];                           // initial state
    __shared__ float2 accs[SPB];                           // RK accumulators
    __shared__ float  ucs[SPB];                            // u * b_ctrl
    __shared__ float  slot0[1024], slot1[1024];            // per-wave grad partials
    __shared__ float  dHacc[SPB * 2];                      // folded (dH/dq, dH/dp)

    const int tid  = threadIdx.x;
    const int lane = tid & 63;
    const int wave = tid >> 6;      // 0..15
    const int g    = lane >> 4;     // 0..3
    const int l15  = lane & 15;
    const int col  = wave * 16 + l15;   // 0..255
    // frag-order write base for phC (MFMA C/D-coupled map, R9/R11-proven)
    const int wbase = ((col >> 5) << 9) + (((col >> 3) & 3) << 7) + (col & 7);
    // phA col-pair map: 2 adjacent cols x 4 rows per thread (decoupled)
    const int t8  = l15 & 7;               // col-pair index within strip
    const int rg  = g * 2 + (l15 >> 3);    // row-group 0..7
    const int uA  = rg >> 2;               // subtile (0..1) holding this thread's rows
    const int r0A = (rg & 3) * 4;          // first row within subtile
    const int c0  = wave * 16 + 2 * t8;    // even column
    const int wbA = uA * 4096 + ((c0 >> 5) << 9) + (((c0 >> 3) & 3) << 7) + (c0 & 7);
    // phE read base: h2[kk = wave*16 + g*4 + r][m = l15], r=0..3 contiguous
    const int hbE = (wave >> 1) * 512 + ((wave & 1) * 2 + (g >> 1)) * 128
                  + l15 * 8 + 4 * (g & 1);
    // bpermute byte-indices for the phE A-frag gather
    const int idxLo = ((g << 5) | l15) << 2;
    const int idxHi = idxLo + 64;

    if (tid < SPB) {
        const int sg = blockIdx.x * SPB + tid;
        const float q0 = q_in[sg], p0 = p_in[sg];
        q0p0[tid] = make_float2(q0, p0);
        qps[tid]  = make_float2(q0, p0);
        accs[tid] = make_float2(0.f, 0.f);
        ucs[tid]  = u_in[sg] * bctrl[0];
    }
    __syncthreads();

    const float dt = 0.05f;
    const float LOG2E = 1.44269504f;

    #pragma unroll 1
    for (int st = 0; st < 4; ++st) {
        #pragma unroll 1
        for (int path = 0; path < 2; ++path) {
            const unsigned short* Wf = Wmats + path * 131072;  // row-major W2 [n][k]
            const unsigned short* Wb = Wf + 65536;             // w3-folded W2^T [k][n]
            // phA col-pair params (exp2-domain pre-scale)
            float wqA0, wpA0, b1A0, wqA1, wpA1, b1A1;
            if (path == 0) {
                const float4 wv = *(const float4*)(Wk1 + 2 * c0);
                wqA0 = wv.x * LOG2E; wpA0 = wv.y * LOG2E;
                wqA1 = wv.z * LOG2E; wpA1 = wv.w * LOG2E;
                const float2 bv = *(const float2*)(bk1 + c0);
                b1A0 = bv.x * LOG2E; b1A1 = bv.y * LOG2E;
            } else {
                const float2 wv = *(const float2*)(wp1 + c0);
                wqA0 = wv.x * LOG2E; wqA1 = wv.y * LOG2E;
                wpA0 = 0.f; wpA1 = 0.f;
                const float2 bv = *(const float2*)(bp1 + c0);
                b1A0 = bv.x * LOG2E; b1A1 = bv.y * LOG2E;
            }
            const float b2p = (path ? bp2[col] : bk2[col]) * LOG2E;

            // Weight fragments (R8-proven orientation)
            short8 wfr[8], wbr[8];
            #pragma unroll
            for (int ks = 0; ks < 8; ++ks) {
                wfr[ks] = *(const short8*)(Wf + col * 256 + ks * 32 + g * 8);
                wbr[ks] = *(const short8*)(Wb + col * 256 + ks * 32 + g * 8);
            }

            // w1 B-frag for the phE MFMA: B[k][c] = w1[wave*16+k][c], k<16, c<2 (else 0).
            short8 w1f;
            {
                union { int iv[4]; short8 sv; } uu;
                #pragma unroll
                for (int d = 0; d < 4; ++d) {
                    float lo = 0.f, hi = 0.f;
                    if (g < 2 && l15 < 2) {
                        const int k0 = wave * 16 + g * 8 + 2 * d;
                        if (path == 0) {
                            lo = Wk1[2*k0 + l15];
                            hi = Wk1[2*k0 + 2 + l15];
                        } else if (l15 == 0) {
                            lo = wp1[k0]; hi = wp1[k0 + 1];
                        }
                    }
                    uu.iv[d] = cvt_pk_bf16(lo, hi);
                }
                w1f = uu.sv;
            }

            f32x4 ac, bc;

            // phase A: h2 = log2(1+2^a) for pair -> HB, paired b32 writes
            auto phA = [&](int pair, unsigned short* HB) {
                const int mb = pair * 32 + uA * 16 + r0A;
                #pragma unroll
                for (int i = 0; i < 4; i += 2) {
                    const float4 q2 = *(const float4*)&qps[mb + i];   // rows i, i+1
                    const float a00 = fmaf(wqA0, q2.x, fmaf(wpA0, q2.y, b1A0));
                    const float a01 = fmaf(wqA1, q2.x, fmaf(wpA1, q2.y, b1A1));
                    const float a10 = fmaf(wqA0, q2.z, fmaf(wpA0, q2.w, b1A0));
                    const float a11 = fmaf(wqA1, q2.z, fmaf(wpA1, q2.w, b1A1));
                    const float h00 = flog2(1.0f + fexp2(a00));
                    const float h01 = flog2(1.0f + fexp2(a01));
                    const float h10 = flog2(1.0f + fexp2(a10));
                    const float h11 = flog2(1.0f + fexp2(a11));
                    *(unsigned int*)(HB + wbA + (r0A + i    ) * 8) = cvt_pk_bf16(h00, h01);
                    *(unsigned int*)(HB + wbA + (r0A + i + 1) * 8) = cvt_pk_bf16(h10, h11);
                }
            };
            // phase B: fwd GEMM on subtile u
            auto phB = [&](const unsigned short* HB, int u) {
                ac = (f32x4){0.f, 0.f, 0.f, 0.f};
                #pragma unroll
                for (int ks = 0; ks < 8; ++ks) {
                    const short8 af = *(const short8*)(HB + u*4096 + ks*512 + lane*8);
                    ac = __builtin_amdgcn_mfma_f32_16x16x32_bf16(af, wfr[ks], ac, 0,0,0);
                }
            };
            // phase C: sigma(a2+b2) -> GB  (w3 folded into bwd weights)
            auto phC = [&](unsigned short* GB, int u) {
                #pragma unroll
                for (int r = 0; r < 4; r += 2) {
                    float gg[2];
                    #pragma unroll
                    for (int v = 0; v < 2; ++v) {
                        const float e = fexp2(ac[r+v] + b2p);
                        gg[v] = e * __builtin_amdgcn_rcpf(1.0f + e);
                    }
                    const unsigned int pk = cvt_pk_bf16(gg[0], gg[1]);
                    GB[u*4096 + wbase + (g*4 + r    ) * 8] = (unsigned short)(pk & 0xffffu);
                    GB[u*4096 + wbase + (g*4 + r + 1) * 8] = (unsigned short)(pk >> 16);
                }
            };
            // phase D: bwd GEMM, transposed output via operand swap
            auto phD = [&](const unsigned short* GB, int u) {
                bc = (f32x4){0.f, 0.f, 0.f, 0.f};
                #pragma unroll
                for (int ns = 0; ns < 8; ++ns) {
                    const short8 ag = *(const short8*)(GB + u*4096 + ns*512 + lane*8);
                    bc = __builtin_amdgcn_mfma_f32_16x16x32_bf16(wbr[ns], ag, bc, 0,0,0);
                }
            };
            // phase E: s1 = 1 - 2^(-h2); gather g1 to A-frag; MFMA vs w1f -> slot
            auto phE = [&](const unsigned short* HB, int u, float* slot) {
                const ushort4v hv = *(const ushort4v*)(HB + u*4096 + hbE);
                float v0, v1, v2, v3;
                {
                    const float h0 = __uint_as_float((unsigned)hv[0] << 16);
                    const float h1 = __uint_as_float((unsigned)hv[1] << 16);
                    const float h2 = __uint_as_float((unsigned)hv[2] << 16);
                    const float h3 = __uint_as_float((unsigned)hv[3] << 16);
                    v0 = bc[0] * (1.0f - fexp2(-h0));
                    v1 = bc[1] * (1.0f - fexp2(-h1));
                    v2 = bc[2] * (1.0f - fexp2(-h2));
                    v3 = bc[3] * (1.0f - fexp2(-h3));
                }
                const int pk01 = (int)cvt_pk_bf16(v0, v1);
                const int pk23 = (int)cvt_pk_bf16(v2, v3);
                union { int iv[4]; short8 sv; } af;
                af.iv[0] = __builtin_amdgcn_ds_bpermute(idxLo, pk01);
                af.iv[1] = __builtin_amdgcn_ds_bpermute(idxLo, pk23);
                af.iv[2] = __builtin_amdgcn_ds_bpermute(idxHi, pk01);
                af.iv[3] = __builtin_amdgcn_ds_bpermute(idxHi, pk23);
                f32x4 dd = (f32x4){0.f, 0.f, 0.f, 0.f};
                dd = __builtin_amdgcn_mfma_f32_16x16x32_bf16(af.sv, w1f, dd, 0,0,0);
                if (l15 < 2) {
                    #pragma unroll
                    for (int r = 0; r < 4; ++r)
                        slot[wave*64 + (u*16 + g*4 + r)*2 + l15] = dd[r];
                }
            };
            // phase F: fold 16 wave-partials of a PAIR into dHacc
            auto phF = [&](int pair, const float* slot) {
                if (tid < 64) {
                    const int m2 = tid >> 1, c = tid & 1;
                    if (path == 0 || c == 0) {
                        float s = 0.f;
                        #pragma unroll
                        for (int w = 0; w < 16; ++w) s += slot[w * 64 + tid];
                        const int di = (pair * 32 + m2) * 2 + c;
                        if (path == 0) dHacc[di] = s;
                        else           dHacc[di] += s;
                    }
                }
            };

            // ---- software pipeline over 16 pairs (R11 schedule) ----
            phA(0, bufH0);
            __syncthreads();
            phB(bufH0,0); phC(bufG0,0); phB(bufH0,1); phC(bufG0,1);
            phA(1, bufH1);
            __syncthreads();

            #pragma unroll 1
            for (int k2 = 0; k2 < 7; ++k2) {
                const int j = 1 + 2*k2;   // odd region: pairs j / j-1 / j+1
                phB(bufH1,0); phD(bufG0,0); phC(bufG1,0); phE(bufH0, 0, slot0);
                phB(bufH1,1); phD(bufG0,1); phC(bufG1,1); phE(bufH0, 1, slot0);
                if (k2) phF(j - 2, slot1);
                phA(j + 1, bufH0);       // overwrite AFTER phE read (same-wave order)
                __syncthreads();
                // even region j+1
                phB(bufH0,0); phD(bufG1,0); phC(bufG0,0); phE(bufH1, 0, slot1);
                phB(bufH0,1); phD(bufG1,1); phC(bufG0,1); phE(bufH1, 1, slot1);
                phF(j - 1, slot0);
                phA(j + 2, bufH1);
                __syncthreads();
            }

            // pair 15 (odd): B/C(15), D/E(14), F(13)
            phB(bufH1,0); phD(bufG0,0); phC(bufG1,0); phE(bufH0, 0, slot0);
            phB(bufH1,1); phD(bufG0,1); phC(bufG1,1); phE(bufH0, 1, slot0);
            phF(13, slot1);
            __syncthreads();
            // drain: D/E(15), F(14)
            phD(bufG1,0); phE(bufH1, 0, slot1);
            phD(bufG1,1); phE(bufH1, 1, slot1);
            phF(14, slot0);
            __syncthreads();
            phF(15, slot1);
            __syncthreads();
        } // path

        // ---- stage combine: dq = dH/dp, dp = -dH/dq + u*bc; RK4 update
        if (tid < SPB) {
            const float dq = dHacc[tid * 2 + 1];
            const float dp = -dHacc[tid * 2 + 0] + ucs[tid];
            const float c = (st == 1 || st == 2) ? 2.f : 1.f;
            float2 acc = accs[tid];
            acc.x += c * dq; acc.y += c * dp;
            accs[tid] = acc;
            if (st < 3) {
                const float hh = (st == 2) ? dt : 0.5f * dt;
                const float2 z0 = q0p0[tid];
                qps[tid] = make_float2(z0.x + hh * dq, z0.y + hh * dp);
            }
        }
        __syncthreads();
    }

    if (tid < SPB) {
        const int sg = blockIdx.x * SPB + tid;
        const float2 z0 = q0p0[tid];
        const float2 acc = accs[tid];
        out_q[sg] = z0.x + (dt / 6.f) * acc.x;
        out_p[sg] = z0.y + (dt / 6.f) * acc.y;
    }
}

extern "C" void kernel_launch(void* const* d_in, const int* in_sizes, int n_in,
                              void* d_out, int out_size, void* d_ws, size_t ws_size,
                              hipStream_t stream) {
    const float* q   = (const float*)d_in[0];
    const float* p   = (const float*)d_in[1];
    const float* u   = (const float*)d_in[2];
    const float* Wk1 = (const float*)d_in[3];
    const float* bk1 = (const float*)d_in[4];
    const float* Wk2 = (const float*)d_in[5];
    const float* bk2 = (const float*)d_in[6];
    const float* Wk3 = (const float*)d_in[7];
    const float* Wp1 = (const float*)d_in[9];
    const float* bp1 = (const float*)d_in[10];
    const float* Wp2 = (const float*)d_in[11];
    const float* bp2 = (const float*)d_in[12];
    const float* Wp3 = (const float*)d_in[13];
    const float* bc  = (const float*)d_in[15];

    unsigned short* wbf = (unsigned short*)d_ws;   // 512 KB used
    prep_weights<<<256, 256, 0, stream>>>(Wk2, Wp2, Wk3, Wp3, wbf);

    float* oq = (float*)d_out;
    phgn_main<<<NB / SPB, TPB, 0, stream>>>(q, p, u, Wk1, bk1, bk2, Wk3, Wp1, bp1, bp2, Wp3,
                                            bc, wbf, oq, oq + NB);
}

// Round 15
// 412.075 us; speedup vs baseline: 3.6892x; 1.0056x over previous
//
#include <hip/hip_runtime.h>
#include <hip/hip_bf16.h>

#define NB   131072
#define TPB  1024
#define SPB  512

typedef __attribute__((ext_vector_type(8))) short short8;
typedef __attribute__((ext_vector_type(4))) float f32x4;
typedef __attribute__((ext_vector_type(4))) unsigned short ushort4v;

__device__ __forceinline__ unsigned short f2bf(float f) {
    union { float f; unsigned int u; } v; v.f = f;
    unsigned int r = v.u + 0x7fff + ((v.u >> 16) & 1);   // RNE
    return (unsigned short)(r >> 16);
}

__device__ __forceinline__ unsigned int cvt_pk_bf16(float lo, float hi) {
    unsigned int r;
    asm("v_cvt_pk_bf16_f32 %0, %1, %2" : "=v"(r) : "v"(lo), "v"(hi));
    return r;
}
// native 2^x / log2(x) (v_exp_f32 / v_log_f32 are base-2)
__device__ __forceinline__ float fexp2(float x) {
    float r; asm("v_exp_f32 %0, %1" : "=v"(r) : "v"(x)); return r;
}
__device__ __forceinline__ float flog2(float x) {
    float r; asm("v_log_f32 %0, %1" : "=v"(r) : "v"(x)); return r;
}

// ws layout (ushort elems): [0) Wk2 bf16 row-major [n][k] (fwd, unscaled);
// [65536) Wk2^T·w3 [k][n] (bwd, w3-folded); [131072) Wp2; [196608) Wp2^T·wp3.
// 512 KB, L2-resident.
__global__ void prep_weights(const float* __restrict__ Wk2, const float* __restrict__ Wp2,
                             const float* __restrict__ wk3, const float* __restrict__ wp3,
                             unsigned short* __restrict__ out) {
    int idx = blockIdx.x * blockDim.x + threadIdx.x;   // 0..65535
    int n = idx >> 8, k = idx & 255;
    out[idx]                  = f2bf(Wk2[idx]);
    out[65536 + k * 256 + n]  = f2bf(Wk2[idx] * wk3[n]);
    out[131072 + idx]         = f2bf(Wp2[idx]);
    out[196608 + k * 256 + n] = f2bf(Wp2[idx] * wp3[n]);
}

// Wave w owns col-strip [16w,16w+16); col = 16w + l15 for MFMA-coupled phases
// (C, E).  Pair of 16-row subtiles (32 samples) per barrier region (R11 sched).
// Subtile packed frag-order (16 rows x 256 cols = 4096 ushorts):
//   elem (m,k) at u*4096 + (k>>5)*512 + ((k>>3)&3)*128 + m*8 + (k&7)
// exp2-domain: HB stores h2 = log2(1+e^a); fwd MFMA output IS the layer-2 exp2
// argument (b2 pre-scaled); sigma(a1) recovered in phE as 1 - 2^(-h2).
// Gradient partials: per-wave private slabs gqp[wave][sample][2] (64 KB) —
// phE writes only its own wave's slab (no cross-wave traffic, no per-region
// fold); ONE 16-way fold per stage in the stage combine.
__launch_bounds__(TPB, 4)
__global__ void phgn_main(const float* __restrict__ q_in, const float* __restrict__ p_in,
                          const float* __restrict__ u_in,
                          const float* __restrict__ Wk1, const float* __restrict__ bk1,
                          const float* __restrict__ bk2, const float* __restrict__ wk3,
                          const float* __restrict__ wp1, const float* __restrict__ bp1,
                          const float* __restrict__ bp2, const float* __restrict__ wp3,
                          const float* __restrict__ bctrl,
                          const unsigned short* __restrict__ Wmats,
                          float* __restrict__ out_q, float* __restrict__ out_p) {
    __shared__ unsigned short bufH0[8192], bufH1[8192];    // h2 tile-pairs, 16 KB each
    __shared__ unsigned short bufG0[8192], bufG1[8192];    // g2 tile-pairs
    __shared__ float2 qps[SPB];                            // RK stage state (q,p)
    __shared__ float2 q0p0[SPB];                           // initial state
    __shared__ float2 accs[SPB];                           // RK accumulators
    __shared__ float  ucs[SPB];                            // u * b_ctrl
    __shared__ float  gqp[16 * SPB * 2];                   // per-wave grad slabs, 64 KB

    const int tid  = threadIdx.x;
    const int lane = tid & 63;
    const int wave = tid >> 6;      // 0..15
    const int g    = lane >> 4;     // 0..3
    const int l15  = lane & 15;
    const int col  = wave * 16 + l15;   // 0..255
    // frag-order write base for phC (MFMA C/D-coupled map, R9/R11-proven)
    const int wbase = ((col >> 5) << 9) + (((col >> 3) & 3) << 7) + (col & 7);
    // phA col-pair map: 2 adjacent cols x 4 rows per thread (decoupled)
    const int t8  = l15 & 7;               // col-pair index within strip
    const int rg  = g * 2 + (l15 >> 3);    // row-group 0..7
    const int uA  = rg >> 2;               // subtile (0..1) holding this thread's rows
    const int r0A = (rg & 3) * 4;          // first row within subtile
    const int c0  = wave * 16 + 2 * t8;    // even column
    const int wbA = uA * 4096 + ((c0 >> 5) << 9) + (((c0 >> 3) & 3) << 7) + (c0 & 7);
    // phE read base: h2[kk = wave*16 + g*4 + r][m = l15], r=0..3 contiguous
    const int hbE = (wave >> 1) * 512 + ((wave & 1) * 2 + (g >> 1)) * 128
                  + l15 * 8 + 4 * (g & 1);
    // bpermute byte-indices for the phE A-frag gather
    const int idxLo = ((g << 5) | l15) << 2;
    const int idxHi = idxLo + 64;

    if (tid < SPB) {
        const int sg = blockIdx.x * SPB + tid;
        const float q0 = q_in[sg], p0 = p_in[sg];
        q0p0[tid] = make_float2(q0, p0);
        qps[tid]  = make_float2(q0, p0);
        accs[tid] = make_float2(0.f, 0.f);
        ucs[tid]  = u_in[sg] * bctrl[0];
    }
    __syncthreads();

    const float dt = 0.05f;
    const float LOG2E = 1.44269504f;

    #pragma unroll 1
    for (int st = 0; st < 4; ++st) {
        #pragma unroll 1
        for (int path = 0; path < 2; ++path) {
            const unsigned short* Wf = Wmats + path * 131072;  // row-major W2 [n][k]
            const unsigned short* Wb = Wf + 65536;             // w3-folded W2^T [k][n]
            // phA col-pair params (exp2-domain pre-scale)
            float wqA0, wpA0, b1A0, wqA1, wpA1, b1A1;
            if (path == 0) {
                const float4 wv = *(const float4*)(Wk1 + 2 * c0);
                wqA0 = wv.x * LOG2E; wpA0 = wv.y * LOG2E;
                wqA1 = wv.z * LOG2E; wpA1 = wv.w * LOG2E;
                const float2 bv = *(const float2*)(bk1 + c0);
                b1A0 = bv.x * LOG2E; b1A1 = bv.y * LOG2E;
            } else {
                const float2 wv = *(const float2*)(wp1 + c0);
                wqA0 = wv.x * LOG2E; wqA1 = wv.y * LOG2E;
                wpA0 = 0.f; wpA1 = 0.f;
                const float2 bv = *(const float2*)(bp1 + c0);
                b1A0 = bv.x * LOG2E; b1A1 = bv.y * LOG2E;
            }
            const float b2p = (path ? bp2[col] : bk2[col]) * LOG2E;

            // Weight fragments (R8-proven orientation)
            short8 wfr[8], wbr[8];
            #pragma unroll
            for (int ks = 0; ks < 8; ++ks) {
                wfr[ks] = *(const short8*)(Wf + col * 256 + ks * 32 + g * 8);
                wbr[ks] = *(const short8*)(Wb + col * 256 + ks * 32 + g * 8);
            }

            // w1 B-frag for the phE MFMA: B[k][c] = w1[wave*16+k][c], k<16, c<2 (else 0).
            short8 w1f;
            {
                union { int iv[4]; short8 sv; } uu;
                #pragma unroll
                for (int d = 0; d < 4; ++d) {
                    float lo = 0.f, hi = 0.f;
                    if (g < 2 && l15 < 2) {
                        const int k0 = wave * 16 + g * 8 + 2 * d;
                        if (path == 0) {
                            lo = Wk1[2*k0 + l15];
                            hi = Wk1[2*k0 + 2 + l15];
                        } else if (l15 == 0) {
                            lo = wp1[k0]; hi = wp1[k0 + 1];
                        }
                    }
                    uu.iv[d] = cvt_pk_bf16(lo, hi);
                }
                w1f = uu.sv;
            }

            f32x4 ac, bc;

            // phase A: h2 = log2(1+2^a) for pair -> HB, paired b32 writes
            auto phA = [&](int pair, unsigned short* HB) {
                const int mb = pair * 32 + uA * 16 + r0A;
                #pragma unroll
                for (int i = 0; i < 4; i += 2) {
                    const float4 q2 = *(const float4*)&qps[mb + i];   // rows i, i+1
                    const float a00 = fmaf(wqA0, q2.x, fmaf(wpA0, q2.y, b1A0));
                    const float a01 = fmaf(wqA1, q2.x, fmaf(wpA1, q2.y, b1A1));
                    const float a10 = fmaf(wqA0, q2.z, fmaf(wpA0, q2.w, b1A0));
                    const float a11 = fmaf(wqA1, q2.z, fmaf(wpA1, q2.w, b1A1));
                    const float h00 = flog2(1.0f + fexp2(a00));
                    const float h01 = flog2(1.0f + fexp2(a01));
                    const float h10 = flog2(1.0f + fexp2(a10));
                    const float h11 = flog2(1.0f + fexp2(a11));
                    *(unsigned int*)(HB + wbA + (r0A + i    ) * 8) = cvt_pk_bf16(h00, h01);
                    *(unsigned int*)(HB + wbA + (r0A + i + 1) * 8) = cvt_pk_bf16(h10, h11);
                }
            };
            // phase B: fwd GEMM on subtile u
            auto phB = [&](const unsigned short* HB, int u) {
                ac = (f32x4){0.f, 0.f, 0.f, 0.f};
                #pragma unroll
                for (int ks = 0; ks < 8; ++ks) {
                    const short8 af = *(const short8*)(HB + u*4096 + ks*512 + lane*8);
                    ac = __builtin_amdgcn_mfma_f32_16x16x32_bf16(af, wfr[ks], ac, 0,0,0);
                }
            };
            // phase C: sigma(a2+b2) -> GB  (w3 folded into bwd weights)
            auto phC = [&](unsigned short* GB, int u) {
                #pragma unroll
                for (int r = 0; r < 4; r += 2) {
                    float gg[2];
                    #pragma unroll
                    for (int v = 0; v < 2; ++v) {
                        const float e = fexp2(ac[r+v] + b2p);
                        gg[v] = e * __builtin_amdgcn_rcpf(1.0f + e);
                    }
                    const unsigned int pk = cvt_pk_bf16(gg[0], gg[1]);
                    GB[u*4096 + wbase + (g*4 + r    ) * 8] = (unsigned short)(pk & 0xffffu);
                    GB[u*4096 + wbase + (g*4 + r + 1) * 8] = (unsigned short)(pk >> 16);
                }
            };
            // phase D: bwd GEMM, transposed output via operand swap
            auto phD = [&](const unsigned short* GB, int u) {
                bc = (f32x4){0.f, 0.f, 0.f, 0.f};
                #pragma unroll
                for (int ns = 0; ns < 8; ++ns) {
                    const short8 ag = *(const short8*)(GB + u*4096 + ns*512 + lane*8);
                    bc = __builtin_amdgcn_mfma_f32_16x16x32_bf16(wbr[ns], ag, bc, 0,0,0);
                }
            };
            // phase E: s1 = 1 - 2^(-h2); gather g1 to A-frag; MFMA vs w1f;
            // write/accumulate THIS WAVE's private gqp slab (tp = tile-pair idx).
            auto phE = [&](const unsigned short* HB, int u, int tp) {
                const ushort4v hv = *(const ushort4v*)(HB + u*4096 + hbE);
                float v0, v1, v2, v3;
                {
                    const float h0 = __uint_as_float((unsigned)hv[0] << 16);
                    const float h1 = __uint_as_float((unsigned)hv[1] << 16);
                    const float h2 = __uint_as_float((unsigned)hv[2] << 16);
                    const float h3 = __uint_as_float((unsigned)hv[3] << 16);
                    v0 = bc[0] * (1.0f - fexp2(-h0));
                    v1 = bc[1] * (1.0f - fexp2(-h1));
                    v2 = bc[2] * (1.0f - fexp2(-h2));
                    v3 = bc[3] * (1.0f - fexp2(-h3));
                }
                const int pk01 = (int)cvt_pk_bf16(v0, v1);
                const int pk23 = (int)cvt_pk_bf16(v2, v3);
                union { int iv[4]; short8 sv; } af;
                af.iv[0] = __builtin_amdgcn_ds_bpermute(idxLo, pk01);
                af.iv[1] = __builtin_amdgcn_ds_bpermute(idxLo, pk23);
                af.iv[2] = __builtin_amdgcn_ds_bpermute(idxHi, pk01);
                af.iv[3] = __builtin_amdgcn_ds_bpermute(idxHi, pk23);
                f32x4 dd = (f32x4){0.f, 0.f, 0.f, 0.f};
                dd = __builtin_amdgcn_mfma_f32_16x16x32_bf16(af.sv, w1f, dd, 0,0,0);
                if (l15 < 2) {
                    const int sb = (wave * SPB + tp * 32 + u * 16 + g * 4) * 2 + l15;
                    if (path == 0) {
                        #pragma unroll
                        for (int r = 0; r < 4; ++r) gqp[sb + r * 2] = dd[r];
                    } else {
                        #pragma unroll
                        for (int r = 0; r < 4; ++r) gqp[sb + r * 2] += dd[r];
                    }
                }
            };

            // ---- software pipeline over 16 pairs (R11 schedule, no phF) ----
            phA(0, bufH0);
            __syncthreads();
            phB(bufH0,0); phC(bufG0,0); phB(bufH0,1); phC(bufG0,1);
            phA(1, bufH1);
            __syncthreads();

            #pragma unroll 1
            for (int k2 = 0; k2 < 7; ++k2) {
                const int j = 1 + 2*k2;   // odd region: pairs j / j-1 / j+1
                phB(bufH1,0); phD(bufG0,0); phC(bufG1,0); phE(bufH0, 0, j - 1);
                phB(bufH1,1); phD(bufG0,1); phC(bufG1,1); phE(bufH0, 1, j - 1);
                phA(j + 1, bufH0);       // overwrite AFTER phE read (same-wave order)
                __syncthreads();
                // even region j+1
                phB(bufH0,0); phD(bufG1,0); phC(bufG0,0); phE(bufH1, 0, j);
                phB(bufH0,1); phD(bufG1,1); phC(bufG0,1); phE(bufH1, 1, j);
                phA(j + 2, bufH1);
                __syncthreads();
            }

            // pair 15 (odd): B/C(15), D/E(14)
            phB(bufH1,0); phD(bufG0,0); phC(bufG1,0); phE(bufH0, 0, 14);
            phB(bufH1,1); phD(bufG0,1); phC(bufG1,1); phE(bufH0, 1, 14);
            __syncthreads();
            // drain: D/E(15)
            phD(bufG1,0); phE(bufH1, 0, 15);
            phD(bufG1,1); phE(bufH1, 1, 15);
            __syncthreads();
        } // path

        // ---- stage combine: fold 16 wave slabs; dq = dH/dp, dp = -dH/dq + u*bc
        if (tid < SPB) {
            float sq = 0.f, sp = 0.f;
            #pragma unroll
            for (int w = 0; w < 16; ++w) {
                const float2 v = *(const float2*)&gqp[(w * SPB + tid) * 2];
                sq += v.x; sp += v.y;
            }
            const float dq = sp;
            const float dp = -sq + ucs[tid];
            const float c = (st == 1 || st == 2) ? 2.f : 1.f;
            float2 acc = accs[tid];
            acc.x += c * dq; acc.y += c * dp;
            accs[tid] = acc;
            if (st < 3) {
                const float hh = (st == 2) ? dt : 0.5f * dt;
                const float2 z0 = q0p0[tid];
                qps[tid] = make_float2(z0.x + hh * dq, z0.y + hh * dp);
            }
        }
        __syncthreads();
    }

    if (tid < SPB) {
        const int sg = blockIdx.x * SPB + tid;
        const float2 z0 = q0p0[tid];
        const float2 acc = accs[tid];
        out_q[sg] = z0.x + (dt / 6.f) * acc.x;
        out_p[sg] = z0.y + (dt / 6.f) * acc.y;
    }
}

extern "C" void kernel_launch(void* const* d_in, const int* in_sizes, int n_in,
                              void* d_out, int out_size, void* d_ws, size_t ws_size,
                              hipStream_t stream) {
    const float* q   = (const float*)d_in[0];
    const float* p   = (const float*)d_in[1];
    const float* u   = (const float*)d_in[2];
    const float* Wk1 = (const float*)d_in[3];
    const float* bk1 = (const float*)d_in[4];
    const float* Wk2 = (const float*)d_in[5];
    const float* bk2 = (const float*)d_in[6];
    const float* Wk3 = (const float*)d_in[7];
    const float* Wp1 = (const float*)d_in[9];
    const float* bp1 = (const float*)d_in[10];
    const float* Wp2 = (const float*)d_in[11];
    const float* bp2 = (const float*)d_in[12];
    const float* Wp3 = (const float*)d_in[13];
    const float* bc  = (const float*)d_in[15];

    unsigned short* wbf = (unsigned short*)d_ws;   // 512 KB used
    prep_weights<<<256, 256, 0, stream>>>(Wk2, Wp2, Wk3, Wp3, wbf);

    float* oq = (float*)d_out;
    phgn_main<<<NB / SPB, TPB, 0, stream>>>(q, p, u, Wk1, bk1, bk2, Wk3, Wp1, bp1, bp2, Wp3,
                                            bc, wbf, oq, oq + NB);
}